// Round 5
// baseline (258.606 us; speedup 1.0000x reference)
//
#include <hip/hip_runtime.h>

// MaskAttention: B=4, C=128, H=W=64 -> N=4096
// Round 5: operand reuse. attn: wave = 32q x 32k quadrant (2x A-frag reuse of every
// B-frag), in-tile K-split + end merge, exp2 softmax. qkv: MFMA rewrite.

#define CCH 128
#define NTOK 4096

typedef __attribute__((ext_vector_type(8))) short  bf16x8;
typedef __attribute__((ext_vector_type(4))) float  f32x4;

__device__ __forceinline__ unsigned short f2bf(float f) {
    unsigned int u = __builtin_bit_cast(unsigned int, f);
    u += 0x7FFFu + ((u >> 16) & 1u);      // RNE (finite inputs)
    return (unsigned short)(u >> 16);
}
__device__ __forceinline__ unsigned int pack2bf(float a, float b) {
    return (unsigned int)f2bf(a) | ((unsigned int)f2bf(b) << 16);
}
__device__ __forceinline__ void gload_lds16(const void* g, void* l) {
    __builtin_amdgcn_global_load_lds(
        (const __attribute__((address_space(1))) unsigned int*)g,
        (__attribute__((address_space(3))) unsigned int*)l, 16, 0, 0);
}

// ---------------- k1: QKV projections via MFMA ----------------
// grid 256 (b, 64-token tile), 256 thr. LDS 64KB dynamic:
//   pT @0      [64 tok][256B]  bf16 token-major, b32 cells swizzled: c2 ^= (tok&7)<<3
//   xT @16384  same
//   Wb @32768  [128 co][256B]  bf16, c2 ^= (co&7)<<3
__device__ __forceinline__ void stageW(char* Wb, const float* __restrict__ W, int t) {
    const int co = t >> 1, h = t & 1;
    const float4* src = reinterpret_cast<const float4*>(W + co * CCH + h * 64);
    char* row = Wb + co * 256;
    const int sw = (co & 7) << 3;
    #pragma unroll
    for (int q = 0; q < 16; ++q) {
        const float4 v = src[q];
        const int c2 = h * 32 + q * 2;
        *reinterpret_cast<unsigned int*>(row + (((c2    ) ^ sw) << 2)) = pack2bf(v.x, v.y);
        *reinterpret_cast<unsigned int*>(row + (((c2 + 1) ^ sw) << 2)) = pack2bf(v.z, v.w);
    }
}

__global__ __launch_bounds__(256) void qkv_kernel(
    const float* __restrict__ prompt, const float* __restrict__ xg,
    const float* __restrict__ Wq, const float* __restrict__ bq,
    const float* __restrict__ Wk, const float* __restrict__ bk,
    const float* __restrict__ Wv, const float* __restrict__ bv,
    unsigned short* __restrict__ Qo, unsigned short* __restrict__ Ko,
    unsigned short* __restrict__ Vo)
{
    extern __shared__ __align__(16) char qpool[];
    char* pT = qpool;
    char* xT = qpool + 16384;
    char* Wb = qpool + 32768;

    const int t  = threadIdx.x;
    const int b  = blockIdx.x >> 6;
    const int n0 = (blockIdx.x & 63) << 6;
    const int l  = t & 63;
    const int w  = t >> 6;        // wave -> tokens w*16..+16
    const int g  = l >> 4;
    const int lr = l & 15;

    {   // stage pT/xT: thread t -> channels 2*c2, 2*c2+1; tokens th*16..+16
        const int c2 = t & 63, th = t >> 6;
        const float* ps = prompt + (((size_t)b * CCH + 2 * c2) << 12) + n0 + th * 16;
        const float* xs = xg     + (((size_t)b * CCH + 2 * c2) << 12) + n0 + th * 16;
        float pa[16], pb[16], xa[16], xb[16];
        #pragma unroll
        for (int q = 0; q < 4; ++q) {
            *reinterpret_cast<float4*>(&pa[q*4]) = *reinterpret_cast<const float4*>(ps + q*4);
            *reinterpret_cast<float4*>(&pb[q*4]) = *reinterpret_cast<const float4*>(ps + 4096 + q*4);
            *reinterpret_cast<float4*>(&xa[q*4]) = *reinterpret_cast<const float4*>(xs + q*4);
            *reinterpret_cast<float4*>(&xb[q*4]) = *reinterpret_cast<const float4*>(xs + 4096 + q*4);
        }
        #pragma unroll
        for (int j = 0; j < 16; ++j) {
            const int tok = th * 16 + j;
            const int off = tok * 256 + (((c2) ^ ((tok & 7) << 3)) << 2);
            *reinterpret_cast<unsigned int*>(pT + off) = pack2bf(pa[j], pb[j]);
            *reinterpret_cast<unsigned int*>(xT + off) = pack2bf(xa[j], xb[j]);
        }
    }
    stageW(Wb, Wq, t);
    __syncthreads();

    const float SC2 = 0.12754849f;   // log2(e)/sqrt(128)
    const int swl = (lr & 7) << 3;

    // ---- phase Q (A = pT) ----
    {
        bf16x8 af[4];
        #pragma unroll
        for (int s = 0; s < 4; ++s)
            af[s] = *reinterpret_cast<const bf16x8*>(
                pT + (w * 16 + lr) * 256 + (((s * 16 + g * 4) ^ swl) << 2));
        f32x4 acc[8];
        #pragma unroll
        for (int cf = 0; cf < 8; ++cf) acc[cf] = (f32x4){0.f,0.f,0.f,0.f};
        #pragma unroll
        for (int cf = 0; cf < 8; ++cf)
            #pragma unroll
            for (int s = 0; s < 4; ++s) {
                bf16x8 bf = *reinterpret_cast<const bf16x8*>(
                    Wb + (cf * 16 + lr) * 256 + (((s * 16 + g * 4) ^ swl) << 2));
                acc[cf] = __builtin_amdgcn_mfma_f32_16x16x32_bf16(af[s], bf, acc[cf], 0, 0, 0);
            }
        #pragma unroll
        for (int cf = 0; cf < 8; ++cf) {
            const float bb = bq[cf * 16 + lr];
            #pragma unroll
            for (int i = 0; i < 4; ++i) {
                const int tok = w * 16 + g * 4 + i;
                Qo[((size_t)(b * NTOK + n0 + tok) << 7) + cf * 16 + lr] =
                    f2bf((acc[cf][i] + bb) * SC2);
            }
        }
    }
    __syncthreads();
    stageW(Wb, Wk, t);
    __syncthreads();

    // ---- phase K (A = xT) ----
    bf16x8 af[4];
    #pragma unroll
    for (int s = 0; s < 4; ++s)
        af[s] = *reinterpret_cast<const bf16x8*>(
            xT + (w * 16 + lr) * 256 + (((s * 16 + g * 4) ^ swl) << 2));
    {
        f32x4 acc[8];
        #pragma unroll
        for (int cf = 0; cf < 8; ++cf) acc[cf] = (f32x4){0.f,0.f,0.f,0.f};
        #pragma unroll
        for (int cf = 0; cf < 8; ++cf)
            #pragma unroll
            for (int s = 0; s < 4; ++s) {
                bf16x8 bf = *reinterpret_cast<const bf16x8*>(
                    Wb + (cf * 16 + lr) * 256 + (((s * 16 + g * 4) ^ swl) << 2));
                acc[cf] = __builtin_amdgcn_mfma_f32_16x16x32_bf16(af[s], bf, acc[cf], 0, 0, 0);
            }
        #pragma unroll
        for (int cf = 0; cf < 8; ++cf) {
            const float bb = bk[cf * 16 + lr];
            #pragma unroll
            for (int i = 0; i < 4; ++i) {
                const int tok = w * 16 + g * 4 + i;
                Ko[((size_t)(b * NTOK + n0 + tok) << 7) + cf * 16 + lr] =
                    f2bf(acc[cf][i] + bb);
            }
        }
    }
    __syncthreads();
    stageW(Wb, Wv, t);
    __syncthreads();

    // ---- phase V (A = xT, transposed store) ----
    {
        f32x4 acc[8];
        #pragma unroll
        for (int cf = 0; cf < 8; ++cf) acc[cf] = (f32x4){0.f,0.f,0.f,0.f};
        #pragma unroll
        for (int cf = 0; cf < 8; ++cf)
            #pragma unroll
            for (int s = 0; s < 4; ++s) {
                bf16x8 bf = *reinterpret_cast<const bf16x8*>(
                    Wb + (cf * 16 + lr) * 256 + (((s * 16 + g * 4) ^ swl) << 2));
                acc[cf] = __builtin_amdgcn_mfma_f32_16x16x32_bf16(af[s], bf, acc[cf], 0, 0, 0);
            }
        #pragma unroll
        for (int cf = 0; cf < 8; ++cf) {
            const float bb = bv[cf * 16 + lr];
            unsigned short pk[4];
            #pragma unroll
            for (int i = 0; i < 4; ++i) pk[i] = f2bf(acc[cf][i] + bb);
            *reinterpret_cast<unsigned long long*>(
                Vo + (((size_t)(b * CCH + cf * 16 + lr)) << 12) + n0 + w * 16 + g * 4) =
                *reinterpret_cast<unsigned long long*>(pk);
        }
    }
}

// ---------------- k2: attention ----------------
// 256 thr = 4 waves: wave (qh = wq>>1, kh = wq&1): 32 q-rows (qh), 32 keys of each
// 64-key tile (kh). Dynamic LDS 75776:
//   Ks dbuf @0      2 x 16384   (64 rows x 256B, 16B-chunk XOR (row&7))
//   Vs dbuf @32768  2 x 16384   (128 ch rows x 128B, same swizzle)
//   Ps      @65536  64 rows x 128B (kh-halves of 64B, swizzled)
//   epilogue: mrg @0 (41472B), stg @41472 (33280B); then tstg @0 (33280B)
__device__ __forceinline__ void stage_tile(
    const unsigned short* __restrict__ Kg, const unsigned short* __restrict__ Vg,
    char* KsB, char* VsB, int b, int m0, int w4, int l)
{
    #pragma unroll
    for (int ii = 0; ii < 4; ++ii) {        // K: 4 x 1KB chunks (4 rows each)
        const int i = w4 * 4 + ii;
        const int r = i * 4 + (l >> 4);
        const int csrc = (l & 15) ^ (r & 7);
        const unsigned short* src = Kg + ((size_t)(b * NTOK + m0 + r) << 7) + csrc * 8;
        gload_lds16(src, KsB + i * 1024);
    }
    #pragma unroll
    for (int ii = 0; ii < 4; ++ii) {        // V: 4 x 1KB chunks (8 rows each)
        const int i = w4 * 4 + ii;
        const int r = i * 8 + (l >> 3);
        const int csrc = (l & 7) ^ (r & 7);
        const unsigned short* src = Vg + ((size_t)(b * CCH + r) << 12) + m0 + csrc * 8;
        gload_lds16(src, VsB + i * 1024);
    }
}

__global__ __launch_bounds__(256) void attn_ln_kernel(
    const unsigned short* __restrict__ Qg, const unsigned short* __restrict__ Kg,
    const unsigned short* __restrict__ Vg,
    const int* __restrict__ maskb, const float* __restrict__ xg,
    const float* __restrict__ gamma, const float* __restrict__ beta,
    float* __restrict__ out)
{
    extern __shared__ __align__(16) char pool[];
    char* KsBuf = pool;
    char* VsBuf = pool + 32768;
    char* Ps    = pool + 65536;
    float* mrg  = (float*)pool;
    float* stg  = (float*)(pool + 41472);
    float* tstg = (float*)pool;

    const int bid = (blockIdx.x & 7) * 32 + (blockIdx.x >> 3);   // XCD swizzle
    const int t  = threadIdx.x;
    const int b  = bid >> 6;
    const int n0 = (bid & 63) << 6;
    const int l  = t & 63;
    const int wq = t >> 6;
    const int qh = wq >> 1;       // q half (32 rows)
    const int kh = wq & 1;        // key half of each tile (32 keys)
    const int g  = l >> 4;
    const int lr = l & 15;
    const int swz = (lr & 7) << 4;

    // Q fragments: qf[rf][s] = Q[n0 + qh*32 + rf*16 + lr][s*32 + g*8 ..]
    bf16x8 qf[2][4];
    #pragma unroll
    for (int rf = 0; rf < 2; ++rf) {
        const unsigned short* qp =
            Qg + ((size_t)(b * NTOK + n0 + qh * 32 + rf * 16 + lr)) * CCH + g * 8;
        #pragma unroll
        for (int s = 0; s < 4; ++s)
            qf[rf][s] = *reinterpret_cast<const bf16x8*>(qp + s * 32);
    }

    f32x4 acc[2][8];
    float mrun[2][4], lrun[2][4];
    #pragma unroll
    for (int rf = 0; rf < 2; ++rf) {
        #pragma unroll
        for (int cf = 0; cf < 8; ++cf) acc[rf][cf] = (f32x4){0.f,0.f,0.f,0.f};
        #pragma unroll
        for (int i = 0; i < 4; ++i) { mrun[rf][i] = -1e30f; lrun[rf][i] = 0.f; }
    }

    stage_tile(Kg, Vg, KsBuf, VsBuf, b, 0, wq, l);

    for (int kt = 0; kt < 64; ++kt) {
        __builtin_amdgcn_s_barrier();            // [A]
        __builtin_amdgcn_sched_barrier(0);

        const int m0 = kt << 6;
        int mk[2];
        #pragma unroll
        for (int cf = 0; cf < 2; ++cf)
            mk[cf] = maskb[(size_t)b * NTOK + m0 + kh * 32 + cf * 16 + lr];

        const int tn = (kt + 1) & 63;
        stage_tile(Kg, Vg, KsBuf + (tn & 1) * 16384, VsBuf + (tn & 1) * 16384,
                   b, tn << 6, wq, l);

        asm volatile("s_waitcnt vmcnt(10)" ::: "memory");  // prev stages drained
        __builtin_amdgcn_sched_barrier(0);
        __builtin_amdgcn_s_barrier();            // [B]
        __builtin_amdgcn_sched_barrier(0);

        const char* Ks_c = KsBuf + (kt & 1) * 16384;
        const char* Vs_c = VsBuf + (kt & 1) * 16384;

        // ---- S = Q K^T : 32q x 32k quadrant, kb reused across 2 row-frags ----
        f32x4 sf[2][2];
        #pragma unroll
        for (int rf = 0; rf < 2; ++rf)
            #pragma unroll
            for (int cf = 0; cf < 2; ++cf) sf[rf][cf] = (f32x4){0.f,0.f,0.f,0.f};
        #pragma unroll
        for (int cf = 0; cf < 2; ++cf) {
            const char* rp = Ks_c + (kh * 32 + cf * 16 + lr) * 256;
            #pragma unroll
            for (int s = 0; s < 4; ++s) {
                bf16x8 kb = *reinterpret_cast<const bf16x8*>(rp + ((s * 64 + g * 16) ^ swz));
                sf[0][cf] = __builtin_amdgcn_mfma_f32_16x16x32_bf16(qf[0][s], kb, sf[0][cf], 0, 0, 0);
                sf[1][cf] = __builtin_amdgcn_mfma_f32_16x16x32_bf16(qf[1][s], kb, sf[1][cf], 0, 0, 0);
            }
        }

        // ---- online softmax (exp2 domain; Q pre-scaled by log2e/sqrt(C)) ----
        #pragma unroll
        for (int rf = 0; rf < 2; ++rf) {
            #pragma unroll
            for (int i = 0; i < 4; ++i) {
                float s0 = mk[0] ? sf[rf][0][i] : -1e30f;
                float s1 = mk[1] ? sf[rf][1][i] : -1e30f;
                float rm = fmaxf(s0, s1);
                rm = fmaxf(rm, __shfl_xor(rm, 1));
                rm = fmaxf(rm, __shfl_xor(rm, 2));
                rm = fmaxf(rm, __shfl_xor(rm, 4));
                rm = fmaxf(rm, __shfl_xor(rm, 8));
                const float mn = fmaxf(mrun[rf][i], rm);
                const float cr = exp2f(mrun[rf][i] - mn);
                const float p0 = exp2f(s0 - mn);
                const float p1 = exp2f(s1 - mn);
                float rs = p0 + p1;
                rs += __shfl_xor(rs, 1);
                rs += __shfl_xor(rs, 2);
                rs += __shfl_xor(rs, 4);
                rs += __shfl_xor(rs, 8);
                mrun[rf][i] = mn;
                lrun[rf][i] = lrun[rf][i] * cr + rs;
                #pragma unroll
                for (int cf = 0; cf < 8; ++cf) acc[rf][cf][i] *= cr;
                const int row = qh * 32 + rf * 16 + g * 4 + i;
                char* pb = Ps + row * 128;
                const int rsw = (row & 7) << 4;
                *reinterpret_cast<unsigned short*>(pb + ((kh * 64 + lr * 2     ) ^ rsw)) = f2bf(p0);
                *reinterpret_cast<unsigned short*>(pb + ((kh * 64 + 32 + lr * 2) ^ rsw)) = f2bf(p1);
            }
        }

        // ---- O += P V : vb reused across 2 row-frags ----
        bf16x8 pa[2];
        #pragma unroll
        for (int rf = 0; rf < 2; ++rf)
            pa[rf] = *reinterpret_cast<const bf16x8*>(
                Ps + (qh * 32 + rf * 16 + lr) * 128 + ((kh * 64 + g * 16) ^ swz));
        #pragma unroll
        for (int cf = 0; cf < 8; ++cf) {
            bf16x8 vb = *reinterpret_cast<const bf16x8*>(
                Vs_c + (cf * 16 + lr) * 128 + ((kh * 64 + g * 16) ^ swz));
            acc[0][cf] = __builtin_amdgcn_mfma_f32_16x16x32_bf16(pa[0], vb, acc[0][cf], 0, 0, 0);
            acc[1][cf] = __builtin_amdgcn_mfma_f32_16x16x32_bf16(pa[1], vb, acc[1][cf], 0, 0, 0);
        }
    }

    // ---------------- merge kh halves + residual + LayerNorm + transpose ----------------
    asm volatile("s_waitcnt vmcnt(0)" ::: "memory");
    __syncthreads();

    if (kh == 1) {   // publish partials (stride 81 floats, bank-spread)
        float* dst = mrg + (qh * 64 + l) * 81;
        #pragma unroll
        for (int rf = 0; rf < 2; ++rf) {
            #pragma unroll
            for (int cf = 0; cf < 8; ++cf)
                #pragma unroll
                for (int i = 0; i < 4; ++i) dst[rf * 32 + cf * 4 + i] = acc[rf][cf][i];
            #pragma unroll
            for (int i = 0; i < 4; ++i) {
                dst[64 + rf * 4 + i] = mrun[rf][i];
                dst[72 + rf * 4 + i] = lrun[rf][i];
            }
        }
    }
    {   // stage x tile (c-major, stride 65)
        const int c = t >> 1, nh = (t & 1) << 5;
        const float* src = xg + (((size_t)b * CCH + c) << 12) + n0 + nh;
        float* dst = stg + c * 65 + nh;
        #pragma unroll
        for (int k = 0; k < 32; k += 4) {
            const float4 v = *reinterpret_cast<const float4*>(src + k);
            dst[k] = v.x; dst[k+1] = v.y; dst[k+2] = v.z; dst[k+3] = v.w;
        }
    }
    __syncthreads();

    if (kh == 0) {
        const float* srcm = mrg + (qh * 64 + l) * 81;
        float g8[8], b8[8];
        #pragma unroll
        for (int cf = 0; cf < 8; ++cf) {
            g8[cf] = gamma[cf * 16 + lr];
            b8[cf] = beta[cf * 16 + lr];
        }
        #pragma unroll
        for (int rf = 0; rf < 2; ++rf) {
            #pragma unroll
            for (int i = 0; i < 4; ++i) {
                const float m1 = srcm[64 + rf * 4 + i];
                const float l1 = srcm[72 + rf * 4 + i];
                const float mm = fmaxf(mrun[rf][i], m1);
                const float e0 = exp2f(mrun[rf][i] - mm);
                const float e1 = exp2f(m1 - mm);
                const float inv = 1.f / (lrun[rf][i] * e0 + l1 * e1);
                const int nloc = qh * 32 + rf * 16 + g * 4 + i;
                float sum = 0.f, sq = 0.f;
                #pragma unroll
                for (int cf = 0; cf < 8; ++cf) {
                    const float o = acc[rf][cf][i] * e0 + srcm[rf * 32 + cf * 4 + i] * e1;
                    const float v = o * inv + stg[(cf * 16 + lr) * 65 + nloc];
                    acc[rf][cf][i] = v; sum += v; sq += v * v;
                }
                sum += __shfl_xor(sum, 1); sq += __shfl_xor(sq, 1);
                sum += __shfl_xor(sum, 2); sq += __shfl_xor(sq, 2);
                sum += __shfl_xor(sum, 4); sq += __shfl_xor(sq, 4);
                sum += __shfl_xor(sum, 8); sq += __shfl_xor(sq, 8);
                const float mean = sum * (1.f / 128.f);
                const float var  = sq * (1.f / 128.f) - mean * mean;
                const float rstd = rsqrtf(var + 1e-5f);
                #pragma unroll
                for (int cf = 0; cf < 8; ++cf)
                    acc[rf][cf][i] = (acc[rf][cf][i] - mean) * rstd * g8[cf] + b8[cf];
            }
        }
    }
    __syncthreads();   // mrg reads done; tstg may overwrite

    if (kh == 0) {
        #pragma unroll
        for (int rf = 0; rf < 2; ++rf)
            #pragma unroll
            for (int i = 0; i < 4; ++i) {
                const int nloc = qh * 32 + rf * 16 + g * 4 + i;
                #pragma unroll
                for (int cf = 0; cf < 8; ++cf)
                    tstg[(cf * 16 + lr) * 65 + nloc] = acc[rf][cf][i];
            }
    }
    __syncthreads();

    {   // coalesced transposed store
        const int c = t >> 1, nh = (t & 1) << 5;
        float* dst = out + (((size_t)b * CCH + c) << 12) + n0 + nh;
        const float* srcl = tstg + c * 65 + nh;
        #pragma unroll
        for (int k = 0; k < 32; k += 4) {
            float4 v; v.x = srcl[k]; v.y = srcl[k+1]; v.z = srcl[k+2]; v.w = srcl[k+3];
            *reinterpret_cast<float4*>(dst + k) = v;
        }
    }
}

extern "C" void kernel_launch(void* const* d_in, const int* in_sizes, int n_in,
                              void* d_out, int out_size, void* d_ws, size_t ws_size,
                              hipStream_t stream) {
    const float* prompt = (const float*)d_in[0];
    const float* x      = (const float*)d_in[1];
    const float* Wq     = (const float*)d_in[2];
    const float* bq     = (const float*)d_in[3];
    const float* Wk     = (const float*)d_in[4];
    const float* bk     = (const float*)d_in[5];
    const float* Wv     = (const float*)d_in[6];
    const float* bv     = (const float*)d_in[7];
    const float* gamma  = (const float*)d_in[8];
    const float* beta   = (const float*)d_in[9];
    const int*   maskb  = (const int*)d_in[10];
    float* out = (float*)d_out;

    const size_t M = (size_t)4 * NTOK * CCH;
    unsigned short* Qw = (unsigned short*)d_ws;
    unsigned short* Kw = Qw + M;
    unsigned short* Vw = Kw + M;

    (void)hipFuncSetAttribute((const void*)qkv_kernel,
                              hipFuncAttributeMaxDynamicSharedMemorySize, 65536);
    (void)hipFuncSetAttribute((const void*)attn_ln_kernel,
                              hipFuncAttributeMaxDynamicSharedMemorySize, 75776);

    qkv_kernel<<<256, 256, 65536, stream>>>(prompt, x, Wq, bq, Wk, bk, Wv, bv, Qw, Kw, Vw);
    attn_ln_kernel<<<256, 256, 75776, stream>>>(Qw, Kw, Vw, maskb, x, gamma, beta, out);
}

// Round 6
// 120.034 us; speedup vs baseline: 2.1544x; 2.1544x over previous
//
#include <hip/hip_runtime.h>

// MaskAttention: B=4, C=128, H=W=64 -> N=4096
// Round 6: 8 waves = (qh x kj x h), 32q x 32k per wave (2x B-frag reuse),
// swapped QK^T (lane-local softmax rows), transposed PV, mask-as-multiplier,
// exact rescale-skip, deferred row-sum, 4-way flash merge + fused LN epilogue.

#define CCH 128
#define NTOK 4096

typedef __attribute__((ext_vector_type(8))) short  bf16x8;
typedef __attribute__((ext_vector_type(8))) unsigned short ushort8;
typedef __attribute__((ext_vector_type(4))) float  f32x4;

__device__ __forceinline__ unsigned short f2bf(float f) {
    unsigned int u = __builtin_bit_cast(unsigned int, f);
    u += 0x7FFFu + ((u >> 16) & 1u);      // RNE (finite inputs)
    return (unsigned short)(u >> 16);
}
__device__ __forceinline__ unsigned int pack2bf(float a, float b) {
    return (unsigned int)f2bf(a) | ((unsigned int)f2bf(b) << 16);
}
__device__ __forceinline__ void gload_lds16(const void* g, void* l) {
    __builtin_amdgcn_global_load_lds(
        (const __attribute__((address_space(1))) unsigned int*)g,
        (__attribute__((address_space(3))) unsigned int*)l, 16, 0, 0);
}

// ---------------- k1: QKV projections via MFMA (round-5, unchanged) ----------------
__device__ __forceinline__ void stageW(char* Wb, const float* __restrict__ W, int t) {
    const int co = t >> 1, h = t & 1;
    const float4* src = reinterpret_cast<const float4*>(W + co * CCH + h * 64);
    char* row = Wb + co * 256;
    const int sw = (co & 7) << 3;
    #pragma unroll
    for (int q = 0; q < 16; ++q) {
        const float4 v = src[q];
        const int c2 = h * 32 + q * 2;
        *reinterpret_cast<unsigned int*>(row + (((c2    ) ^ sw) << 2)) = pack2bf(v.x, v.y);
        *reinterpret_cast<unsigned int*>(row + (((c2 + 1) ^ sw) << 2)) = pack2bf(v.z, v.w);
    }
}

__global__ __launch_bounds__(256) void qkv_kernel(
    const float* __restrict__ prompt, const float* __restrict__ xg,
    const float* __restrict__ Wq, const float* __restrict__ bq,
    const float* __restrict__ Wk, const float* __restrict__ bk,
    const float* __restrict__ Wv, const float* __restrict__ bv,
    unsigned short* __restrict__ Qo, unsigned short* __restrict__ Ko,
    unsigned short* __restrict__ Vo)
{
    extern __shared__ __align__(16) char qpool[];
    char* pT = qpool;
    char* xT = qpool + 16384;
    char* Wb = qpool + 32768;

    const int t  = threadIdx.x;
    const int b  = blockIdx.x >> 6;
    const int n0 = (blockIdx.x & 63) << 6;
    const int l  = t & 63;
    const int w  = t >> 6;
    const int g  = l >> 4;
    const int lr = l & 15;

    {
        const int c2 = t & 63, th = t >> 6;
        const float* ps = prompt + (((size_t)b * CCH + 2 * c2) << 12) + n0 + th * 16;
        const float* xs = xg     + (((size_t)b * CCH + 2 * c2) << 12) + n0 + th * 16;
        float pa[16], pb[16], xa[16], xb[16];
        #pragma unroll
        for (int q = 0; q < 4; ++q) {
            *reinterpret_cast<float4*>(&pa[q*4]) = *reinterpret_cast<const float4*>(ps + q*4);
            *reinterpret_cast<float4*>(&pb[q*4]) = *reinterpret_cast<const float4*>(ps + 4096 + q*4);
            *reinterpret_cast<float4*>(&xa[q*4]) = *reinterpret_cast<const float4*>(xs + q*4);
            *reinterpret_cast<float4*>(&xb[q*4]) = *reinterpret_cast<const float4*>(xs + 4096 + q*4);
        }
        #pragma unroll
        for (int j = 0; j < 16; ++j) {
            const int tok = th * 16 + j;
            const int off = tok * 256 + (((c2) ^ ((tok & 7) << 3)) << 2);
            *reinterpret_cast<unsigned int*>(pT + off) = pack2bf(pa[j], pb[j]);
            *reinterpret_cast<unsigned int*>(xT + off) = pack2bf(xa[j], xb[j]);
        }
    }
    stageW(Wb, Wq, t);
    __syncthreads();

    const float SC2 = 0.12754849f;   // log2(e)/sqrt(128)
    const int swl = (lr & 7) << 3;

    {   // phase Q
        bf16x8 af[4];
        #pragma unroll
        for (int s = 0; s < 4; ++s)
            af[s] = *reinterpret_cast<const bf16x8*>(
                pT + (w * 16 + lr) * 256 + (((s * 16 + g * 4) ^ swl) << 2));
        f32x4 acc[8];
        #pragma unroll
        for (int cf = 0; cf < 8; ++cf) acc[cf] = (f32x4){0.f,0.f,0.f,0.f};
        #pragma unroll
        for (int cf = 0; cf < 8; ++cf)
            #pragma unroll
            for (int s = 0; s < 4; ++s) {
                bf16x8 bf = *reinterpret_cast<const bf16x8*>(
                    Wb + (cf * 16 + lr) * 256 + (((s * 16 + g * 4) ^ swl) << 2));
                acc[cf] = __builtin_amdgcn_mfma_f32_16x16x32_bf16(af[s], bf, acc[cf], 0, 0, 0);
            }
        #pragma unroll
        for (int cf = 0; cf < 8; ++cf) {
            const float bb = bq[cf * 16 + lr];
            #pragma unroll
            for (int i = 0; i < 4; ++i) {
                const int tok = w * 16 + g * 4 + i;
                Qo[((size_t)(b * NTOK + n0 + tok) << 7) + cf * 16 + lr] =
                    f2bf((acc[cf][i] + bb) * SC2);
            }
        }
    }
    __syncthreads();
    stageW(Wb, Wk, t);
    __syncthreads();

    bf16x8 af[4];
    #pragma unroll
    for (int s = 0; s < 4; ++s)
        af[s] = *reinterpret_cast<const bf16x8*>(
            xT + (w * 16 + lr) * 256 + (((s * 16 + g * 4) ^ swl) << 2));
    {   // phase K
        f32x4 acc[8];
        #pragma unroll
        for (int cf = 0; cf < 8; ++cf) acc[cf] = (f32x4){0.f,0.f,0.f,0.f};
        #pragma unroll
        for (int cf = 0; cf < 8; ++cf)
            #pragma unroll
            for (int s = 0; s < 4; ++s) {
                bf16x8 bf = *reinterpret_cast<const bf16x8*>(
                    Wb + (cf * 16 + lr) * 256 + (((s * 16 + g * 4) ^ swl) << 2));
                acc[cf] = __builtin_amdgcn_mfma_f32_16x16x32_bf16(af[s], bf, acc[cf], 0, 0, 0);
            }
        #pragma unroll
        for (int cf = 0; cf < 8; ++cf) {
            const float bb = bk[cf * 16 + lr];
            #pragma unroll
            for (int i = 0; i < 4; ++i) {
                const int tok = w * 16 + g * 4 + i;
                Ko[((size_t)(b * NTOK + n0 + tok) << 7) + cf * 16 + lr] =
                    f2bf(acc[cf][i] + bb);
            }
        }
    }
    __syncthreads();
    stageW(Wb, Wv, t);
    __syncthreads();

    {   // phase V (transposed store)
        f32x4 acc[8];
        #pragma unroll
        for (int cf = 0; cf < 8; ++cf) acc[cf] = (f32x4){0.f,0.f,0.f,0.f};
        #pragma unroll
        for (int cf = 0; cf < 8; ++cf)
            #pragma unroll
            for (int s = 0; s < 4; ++s) {
                bf16x8 bf = *reinterpret_cast<const bf16x8*>(
                    Wb + (cf * 16 + lr) * 256 + (((s * 16 + g * 4) ^ swl) << 2));
                acc[cf] = __builtin_amdgcn_mfma_f32_16x16x32_bf16(af[s], bf, acc[cf], 0, 0, 0);
            }
        #pragma unroll
        for (int cf = 0; cf < 8; ++cf) {
            const float bb = bv[cf * 16 + lr];
            unsigned short pk[4];
            #pragma unroll
            for (int i = 0; i < 4; ++i) pk[i] = f2bf(acc[cf][i] + bb);
            *reinterpret_cast<unsigned long long*>(
                Vo + (((size_t)(b * CCH + cf * 16 + lr)) << 12) + n0 + w * 16 + g * 4) =
                *reinterpret_cast<unsigned long long*>(pk);
        }
    }
}

// ---------------- k2: attention ----------------
// 512 thr = 8 waves: wq -> h = wq>>2 (K-range half), kj = (wq>>1)&1 (key half of
// tile), qh = wq&1 (q half). Dynamic LDS 147456:
//   h0: K dbuf @0 (2x16384), V dbuf @32768 ; h1: K @65536, V @98304
//   P @131072: 8 waves x 2048 (32 q-rows x 64B, 16B-chunk ^ (q&3))
//   epilogue reuse: merge regions @0 (6 x 17664B), stg @105984 (128x65 f32)
__device__ __forceinline__ void stage_tile(
    const unsigned short* __restrict__ Kg, const unsigned short* __restrict__ Vg,
    char* KsB, char* VsB, int b, int m0, int w4, int l)
{
    #pragma unroll
    for (int ii = 0; ii < 4; ++ii) {        // K: 4 x 1KB chunks (4 rows each)
        const int i = w4 * 4 + ii;
        const int r = i * 4 + (l >> 4);
        const int csrc = (l & 15) ^ (r & 7);
        const unsigned short* src = Kg + ((size_t)(b * NTOK + m0 + r) << 7) + csrc * 8;
        gload_lds16(src, KsB + i * 1024);
    }
    #pragma unroll
    for (int ii = 0; ii < 4; ++ii) {        // V: 4 x 1KB chunks (8 rows each)
        const int i = w4 * 4 + ii;
        const int r = i * 8 + (l >> 3);
        const int csrc = (l & 7) ^ (r & 7);
        const unsigned short* src = Vg + ((size_t)(b * CCH + r) << 12) + m0 + csrc * 8;
        gload_lds16(src, VsB + i * 1024);
    }
}

__global__ __launch_bounds__(512) void attn_ln_kernel(
    const unsigned short* __restrict__ Qg, const unsigned short* __restrict__ Kg,
    const unsigned short* __restrict__ Vg,
    const int* __restrict__ maskb, const float* __restrict__ xg,
    const float* __restrict__ gamma, const float* __restrict__ beta,
    float* __restrict__ out)
{
    extern __shared__ __align__(16) char pool[];

    const int bid = (blockIdx.x & 7) * 32 + (blockIdx.x >> 3);   // XCD swizzle
    const int t  = threadIdx.x;
    const int b  = bid >> 6;
    const int n0 = (bid & 63) << 6;
    const int l  = t & 63;
    const int wq = t >> 6;
    const int h  = wq >> 2;
    const int kj = (wq >> 1) & 1;
    const int qh = wq & 1;
    const int w4 = wq & 3;
    const int g  = l >> 4;
    const int lr = l & 15;
    const int swz = (lr & 7) << 4;
    const int base_m = h << 11;

    char* KsH = pool + h * 65536;
    char* VsH = pool + h * 65536 + 32768;
    char* Pw  = pool + 131072 + wq * 2048;

    // Q fragments (B-operand): lane holds Q[n0+qh*32+rf*16+lr][s*32 + g*8 + j]
    bf16x8 qf[2][4];
    #pragma unroll
    for (int rf = 0; rf < 2; ++rf) {
        const unsigned short* qp =
            Qg + ((size_t)(b * NTOK + n0 + qh * 32 + rf * 16 + lr)) * CCH + g * 8;
        #pragma unroll
        for (int s = 0; s < 4; ++s)
            qf[rf][s] = *reinterpret_cast<const bf16x8*>(qp + s * 32);
    }

    // acc transposed: acc[rf][cfv][i] = O[ch = cfv*16+g*4+i][q = rf*16+lr]
    f32x4 acc[2][8];
    float mrun[2], lrun[2];
    #pragma unroll
    for (int rf = 0; rf < 2; ++rf) {
        #pragma unroll
        for (int cf = 0; cf < 8; ++cf) acc[rf][cf] = (f32x4){0.f,0.f,0.f,0.f};
        mrun[rf] = -1e30f; lrun[rf] = 0.f;
    }

    stage_tile(Kg, Vg, KsH, VsH, b, base_m, w4, l);

    for (int it = 0; it < 32; ++it) {
        __builtin_amdgcn_s_barrier();            // [A] prev compute reads done
        __builtin_amdgcn_sched_barrier(0);

        const int m0 = base_m + (it << 6);
        const int4 mv0 = *reinterpret_cast<const int4*>(
            maskb + (size_t)b * NTOK + m0 + kj * 32 + g * 4);
        const int4 mv1 = *reinterpret_cast<const int4*>(
            maskb + (size_t)b * NTOK + m0 + kj * 32 + 16 + g * 4);

        const int tn = (it + 1) & 31;
        stage_tile(Kg, Vg, KsH + (tn & 1) * 16384, VsH + (tn & 1) * 16384,
                   b, base_m + (tn << 6), w4, l);

        asm volatile("s_waitcnt vmcnt(10)" ::: "memory");  // own stage(it) drained
        __builtin_amdgcn_sched_barrier(0);
        __builtin_amdgcn_s_barrier();            // [B] stage(it) visible
        __builtin_amdgcn_sched_barrier(0);

        const char* Ks_c = KsH + (it & 1) * 16384;
        const char* Vs_c = VsH + (it & 1) * 16384;

        // ---- S^T = mfma(K, Q): lane holds S[key=kj*32+cf*16+g*4+i][q=rf*16+lr]
        f32x4 sf[2][2];
        #pragma unroll
        for (int rf = 0; rf < 2; ++rf)
            #pragma unroll
            for (int cf = 0; cf < 2; ++cf) sf[rf][cf] = (f32x4){0.f,0.f,0.f,0.f};
        #pragma unroll
        for (int cf = 0; cf < 2; ++cf) {
            const char* rp = Ks_c + (kj * 32 + cf * 16 + lr) * 256;
            #pragma unroll
            for (int s = 0; s < 4; ++s) {
                bf16x8 kb = *reinterpret_cast<const bf16x8*>(rp + ((s * 64 + g * 16) ^ swz));
                sf[0][cf] = __builtin_amdgcn_mfma_f32_16x16x32_bf16(kb, qf[0][s], sf[0][cf], 0, 0, 0);
                sf[1][cf] = __builtin_amdgcn_mfma_f32_16x16x32_bf16(kb, qf[1][s], sf[1][cf], 0, 0, 0);
            }
        }

        const float mk0[4] = { mv0.x ? 1.f : 0.f, mv0.y ? 1.f : 0.f,
                               mv0.z ? 1.f : 0.f, mv0.w ? 1.f : 0.f };
        const float mk1[4] = { mv1.x ? 1.f : 0.f, mv1.y ? 1.f : 0.f,
                               mv1.z ? 1.f : 0.f, mv1.w ? 1.f : 0.f };

        // ---- softmax: row q = rf*16+lr is lane-local across g via shfl 16/32 ----
        #pragma unroll
        for (int rf = 0; rf < 2; ++rf) {
            float rm = fmaxf(
                fmaxf(fmaxf(sf[rf][0][0], sf[rf][0][1]), fmaxf(sf[rf][0][2], sf[rf][0][3])),
                fmaxf(fmaxf(sf[rf][1][0], sf[rf][1][1]), fmaxf(sf[rf][1][2], sf[rf][1][3])));
            rm = fmaxf(rm, __shfl_xor(rm, 16));
            rm = fmaxf(rm, __shfl_xor(rm, 32));
            if (!__all(rm <= mrun[rf])) {        // exact skip: cr==1 when skipped
                const float mn = fmaxf(mrun[rf], rm);
                const float cr = exp2f(mrun[rf] - mn);
                mrun[rf] = mn;
                lrun[rf] *= cr;
                #pragma unroll
                for (int cf = 0; cf < 8; ++cf) {
                    acc[rf][cf][0] *= cr; acc[rf][cf][1] *= cr;
                    acc[rf][cf][2] *= cr; acc[rf][cf][3] *= cr;
                }
            }
            float p0[4], p1[4];
            #pragma unroll
            for (int i = 0; i < 4; ++i) {
                p0[i] = exp2f(sf[rf][0][i] - mrun[rf]) * mk0[i];
                p1[i] = exp2f(sf[rf][1][i] - mrun[rf]) * mk1[i];
            }
            lrun[rf] += ((p0[0] + p0[1]) + (p0[2] + p0[3]))
                      + ((p1[0] + p1[1]) + (p1[2] + p1[3]));
            // write P row (own wave): row=rf*16+lr, 16B-chunk ^= (row&3)
            char* pr = Pw + (rf * 16 + lr) * 64;
            const int ps = lr & 3;
            const int c0 = (g >> 1), o0 = ((g & 1) << 3);
            *reinterpret_cast<unsigned int*>(pr + (((c0    ) ^ ps) << 4) + o0    ) = pack2bf(p0[0], p0[1]);
            *reinterpret_cast<unsigned int*>(pr + (((c0    ) ^ ps) << 4) + o0 + 4) = pack2bf(p0[2], p0[3]);
            *reinterpret_cast<unsigned int*>(pr + (((c0 + 2) ^ ps) << 4) + o0    ) = pack2bf(p1[0], p1[1]);
            *reinterpret_cast<unsigned int*>(pr + (((c0 + 2) ^ ps) << 4) + o0 + 4) = pack2bf(p1[2], p1[3]);
        }

        // ---- O^T += mfma(V, P): vb reused across both rf ----
        bf16x8 pb[2];
        #pragma unroll
        for (int rf = 0; rf < 2; ++rf)
            pb[rf] = *reinterpret_cast<const bf16x8*>(
                Pw + (rf * 16 + lr) * 64 + ((g ^ (lr & 3)) << 4));
        #pragma unroll
        for (int cf = 0; cf < 8; ++cf) {
            bf16x8 vb = *reinterpret_cast<const bf16x8*>(
                Vs_c + (cf * 16 + lr) * 128 + ((kj * 64 + g * 16) ^ swz));
            acc[0][cf] = __builtin_amdgcn_mfma_f32_16x16x32_bf16(vb, pb[0], acc[0][cf], 0, 0, 0);
            acc[1][cf] = __builtin_amdgcn_mfma_f32_16x16x32_bf16(vb, pb[1], acc[1][cf], 0, 0, 0);
        }
    }

    // ---------------- 4-way merge + residual + LayerNorm + transpose ----------------
    asm volatile("s_waitcnt vmcnt(0)" ::: "memory");
    #pragma unroll
    for (int rf = 0; rf < 2; ++rf) {     // finish deferred row sums
        lrun[rf] += __shfl_xor(lrun[rf], 16);
        lrun[rf] += __shfl_xor(lrun[rf], 32);
    }
    __syncthreads();

    const int sub = wq >> 1;             // (h,kj) id 0..3
    float* stg = (float*)(pool + 105984);

    if (sub != 0) {                      // publish partials, stride 69 floats
        float* dst = (float*)pool + ((sub - 1) * 2 + qh) * 4416 + l * 69;
        #pragma unroll
        for (int rf = 0; rf < 2; ++rf)
            #pragma unroll
            for (int cf = 0; cf < 8; ++cf)
                #pragma unroll
                for (int i = 0; i < 4; ++i)
                    dst[rf * 32 + cf * 4 + i] = acc[rf][cf][i];
        dst[64] = mrun[0]; dst[65] = mrun[1];
        dst[66] = lrun[0]; dst[67] = lrun[1];
    }
    {   // stage x tile (c-major, stride 65) — all 512 threads
        const int c = t >> 2, h0 = (t & 3) << 4;
        const float* src = xg + (((size_t)b * CCH + c) << 12) + n0 + h0;
        float* dst = stg + c * 65 + h0;
        #pragma unroll
        for (int k = 0; k < 16; k += 4) {
            const float4 v = *reinterpret_cast<const float4*>(src + k);
            dst[k] = v.x; dst[k+1] = v.y; dst[k+2] = v.z; dst[k+3] = v.w;
        }
    }
    __syncthreads();

    if (sub == 0) {
        const float* r1 = (const float*)pool + (0 * 2 + qh) * 4416 + l * 69;
        const float* r2 = (const float*)pool + (1 * 2 + qh) * 4416 + l * 69;
        const float* r3 = (const float*)pool + (2 * 2 + qh) * 4416 + l * 69;
        float gm[8][4], bt[8][4];
        #pragma unroll
        for (int cf = 0; cf < 8; ++cf)
            #pragma unroll
            for (int i = 0; i < 4; ++i) {
                gm[cf][i] = gamma[cf * 16 + g * 4 + i];
                bt[cf][i] = beta [cf * 16 + g * 4 + i];
            }
        #pragma unroll
        for (int rf = 0; rf < 2; ++rf) {
            const float mA = r1[64 + rf], mB = r2[64 + rf], mC = r3[64 + rf];
            const float lA = r1[66 + rf], lB = r2[66 + rf], lC = r3[66 + rf];
            const float mx = fmaxf(fmaxf(mrun[rf], mA), fmaxf(mB, mC));
            const float e0 = exp2f(mrun[rf] - mx);
            const float eA = exp2f(mA - mx);
            const float eB = exp2f(mB - mx);
            const float eC = exp2f(mC - mx);
            const float inv = 1.f / (lrun[rf] * e0 + lA * eA + lB * eB + lC * eC);
            const int nloc = qh * 32 + rf * 16 + lr;
            float sum = 0.f, sq = 0.f;
            #pragma unroll
            for (int cf = 0; cf < 8; ++cf)
                #pragma unroll
                for (int i = 0; i < 4; ++i) {
                    const int idx = rf * 32 + cf * 4 + i;
                    const float o = acc[rf][cf][i] * e0 + r1[idx] * eA
                                  + r2[idx] * eB + r3[idx] * eC;
                    const float v = o * inv + stg[(cf * 16 + g * 4 + i) * 65 + nloc];
                    acc[rf][cf][i] = v; sum += v; sq += v * v;
                }
            sum += __shfl_xor(sum, 16); sq += __shfl_xor(sq, 16);
            sum += __shfl_xor(sum, 32); sq += __shfl_xor(sq, 32);
            const float mean = sum * (1.f / 128.f);
            const float var  = sq * (1.f / 128.f) - mean * mean;
            const float rstd = rsqrtf(var + 1e-5f);
            #pragma unroll
            for (int cf = 0; cf < 8; ++cf)
                #pragma unroll
                for (int i = 0; i < 4; ++i)
                    stg[(cf * 16 + g * 4 + i) * 65 + nloc] =
                        (acc[rf][cf][i] - mean) * rstd * gm[cf][i] + bt[cf][i];
        }
    }
    __syncthreads();

    {   // coalesced transposed store — all 512 threads
        const int c = t >> 2, h0 = (t & 3) << 4;
        float* dst = out + (((size_t)b * CCH + c) << 12) + n0 + h0;
        const float* srcl = stg + c * 65 + h0;
        #pragma unroll
        for (int k = 0; k < 16; k += 4) {
            float4 v; v.x = srcl[k]; v.y = srcl[k+1]; v.z = srcl[k+2]; v.w = srcl[k+3];
            *reinterpret_cast<float4*>(dst + k) = v;
        }
    }
}

extern "C" void kernel_launch(void* const* d_in, const int* in_sizes, int n_in,
                              void* d_out, int out_size, void* d_ws, size_t ws_size,
                              hipStream_t stream) {
    const float* prompt = (const float*)d_in[0];
    const float* x      = (const float*)d_in[1];
    const float* Wq     = (const float*)d_in[2];
    const float* bq     = (const float*)d_in[3];
    const float* Wk     = (const float*)d_in[4];
    const float* bk     = (const float*)d_in[5];
    const float* Wv     = (const float*)d_in[6];
    const float* bv     = (const float*)d_in[7];
    const float* gamma  = (const float*)d_in[8];
    const float* beta   = (const float*)d_in[9];
    const int*   maskb  = (const int*)d_in[10];
    float* out = (float*)d_out;

    const size_t M = (size_t)4 * NTOK * CCH;
    unsigned short* Qw = (unsigned short*)d_ws;
    unsigned short* Kw = Qw + M;
    unsigned short* Vw = Kw + M;

    (void)hipFuncSetAttribute((const void*)qkv_kernel,
                              hipFuncAttributeMaxDynamicSharedMemorySize, 65536);
    (void)hipFuncSetAttribute((const void*)attn_ln_kernel,
                              hipFuncAttributeMaxDynamicSharedMemorySize, 147456);

    qkv_kernel<<<256, 256, 65536, stream>>>(prompt, x, Wq, bq, Wk, bk, Wv, bv, Qw, Kw, Vw);
    attn_ln_kernel<<<256, 512, 147456, stream>>>(Qw, Kw, Vw, maskb, x, gamma, beta, out);
}